// Round 3
// baseline (2503.312 us; speedup 1.0000x reference)
//
#include <hip/hip_runtime.h>
#include <hip/hip_cooperative_groups.h>
#include <math.h>

namespace cg = cooperative_groups;

#define SEQ 16
#define HID 1024
#define G4 4096
#define LATENT 2048

__device__ __forceinline__ float sigmoidf_(float x) { return 1.f / (1.f + __expf(-x)); }
__device__ __forceinline__ float tanhf_(float x) { return 1.f - 2.f / (__expf(2.f * x) + 1.f); }
__device__ __forceinline__ float dot4(float4 a, float4 b) {
    return a.x * b.x + a.y * b.y + a.z * b.z + a.w * b.w;
}

// ---------------------------------------------------------------------------
// xg0[t][g] = x[t] . w_ih0[g] + b_ih0[g] + b_hh0[g]   (K = 2048)
// 512 blocks x 256 threads; block owns 8 g-rows (2 per wave); x staged in LDS
// in 4 chunks; float4 weight streaming.
// ---------------------------------------------------------------------------
__global__ __launch_bounds__(256) void xg0_gemm(const float* __restrict__ x,
                                                const float* __restrict__ w,
                                                const float* __restrict__ bi,
                                                const float* __restrict__ bh,
                                                float* __restrict__ xg) {
    __shared__ float xs[SEQ][512];  // 32 KB
    const int tid = threadIdx.x, wv = tid >> 6, ln = tid & 63;
    const int g0 = blockIdx.x * 8 + wv * 2;

    float acc0[SEQ], acc1[SEQ];
#pragma unroll
    for (int t = 0; t < SEQ; ++t) { acc0[t] = 0.f; acc1[t] = 0.f; }

    for (int ch = 0; ch < 4; ++ch) {
        __syncthreads();
        const float4* xsrc = (const float4*)x;
#pragma unroll
        for (int i = 0; i < 8; ++i) {
            const int idx = tid + i * 256;
            const int t = idx >> 7;
            const int c = idx & 127;
            ((float4*)xs)[t * 128 + c] = xsrc[t * 512 + ch * 128 + c];
        }
        __syncthreads();
        const float4* w0 = (const float4*)(w + (size_t)g0 * LATENT) + ch * 128;
        const float4* w1 = (const float4*)(w + (size_t)(g0 + 1) * LATENT) + ch * 128;
        const float4 a0 = w0[ln], a1 = w0[ln + 64];
        const float4 b0 = w1[ln], b1 = w1[ln + 64];
#pragma unroll
        for (int t = 0; t < SEQ; ++t) {
            const float4 xa = ((const float4*)xs)[t * 128 + ln];
            const float4 xb = ((const float4*)xs)[t * 128 + ln + 64];
            acc0[t] += dot4(a0, xa) + dot4(a1, xb);
            acc1[t] += dot4(b0, xa) + dot4(b1, xb);
        }
    }
#pragma unroll
    for (int t = 0; t < SEQ; ++t) {
        float v0 = acc0[t], v1 = acc1[t];
#pragma unroll
        for (int off = 32; off; off >>= 1) { v0 += __shfl_xor(v0, off); v1 += __shfl_xor(v1, off); }
        acc0[t] = v0; acc1[t] = v1;
    }
    if (ln < SEQ) {
        xg[ln * G4 + g0]     = acc0[ln] + bi[g0] + bh[g0];
        xg[ln * G4 + g0 + 1] = acc1[ln] + bi[g0 + 1] + bh[g0 + 1];
    }
}

// ---------------------------------------------------------------------------
// Fused two-layer recurrence, software-pipelined; ONE WAVE per block.
// Block j owns hidden unit j of both layers. 12 weight rows in VGPRs.
// phase p: h1[p] = LSTM0(h1[p-1], c0, xg0[p])                    (p<16)
//          h2[p-1] = LSTM1(h2[p-2], c1, W_ih1.h1[p-1]+bias)      (p>=1)
// No LDS, no __syncthreads; one grid.sync per phase (17 total).
// ---------------------------------------------------------------------------
__global__ __launch_bounds__(64) void fused_lstm(
    const float* __restrict__ w_hh0,
    const float* __restrict__ w_ih1,
    const float* __restrict__ w_hh1,
    const float* __restrict__ b_ih1,
    const float* __restrict__ b_hh1,
    const float* __restrict__ xg0,
    float* __restrict__ h1a, float* __restrict__ h1b,
    float* __restrict__ h2a, float* __restrict__ h2b,
    float* __restrict__ out) {
    const int j = blockIdx.x;
    const int ln = threadIdx.x;
    cg::grid_group grid = cg::this_grid();

    // ---- weights into registers: 48 float4 = 192 VGPRs ----
    float4 wa[4][4], wb[4][4], wc[4][4];
#pragma unroll
    for (int g = 0; g < 4; ++g) {
        const float4* p0 = (const float4*)w_hh0 + (size_t)(g * HID + j) * 256;
        const float4* p1 = (const float4*)w_ih1 + (size_t)(g * HID + j) * 256;
        const float4* p2 = (const float4*)w_hh1 + (size_t)(g * HID + j) * 256;
#pragma unroll
        for (int c = 0; c < 4; ++c) {
            wa[g][c] = p0[ln + 64 * c];
            wb[g][c] = p1[ln + 64 * c];
            wc[g][c] = p2[ln + 64 * c];
        }
    }
    float bias1[4];
#pragma unroll
    for (int g = 0; g < 4; ++g) bias1[g] = b_ih1[g * HID + j] + b_hh1[g * HID + j];

    float c0 = 0.f, c1 = 0.f;

    for (int p = 0; p <= SEQ; ++p) {
        const int cur = p & 1;
        const float4* h1r = (const float4*)((p & 1) ? h1a : h1b);  // prev buf
        const float4* h2r = (const float4*)((p & 1) ? h2a : h2b);
        float* h1w = cur ? h1b : h1a;
        float* h2w = cur ? h2b : h2a;

        float d0[4] = {0.f, 0.f, 0.f, 0.f};
        float d1[4] = {0.f, 0.f, 0.f, 0.f};
        float d2[4] = {0.f, 0.f, 0.f, 0.f};
        if (p >= 1) {
#pragma unroll
            for (int c = 0; c < 4; ++c) {
                const float4 h = h1r[ln + 64 * c];
#pragma unroll
                for (int g = 0; g < 4; ++g) {
                    d0[g] += dot4(wa[g][c], h);
                    d1[g] += dot4(wb[g][c], h);
                }
            }
        }
        if (p >= 2) {
#pragma unroll
            for (int c = 0; c < 4; ++c) {
                const float4 h = h2r[ln + 64 * c];
#pragma unroll
                for (int g = 0; g < 4; ++g) d2[g] += dot4(wc[g][c], h);
            }
        }
#pragma unroll
        for (int off = 32; off; off >>= 1) {
#pragma unroll
            for (int g = 0; g < 4; ++g) {
                d0[g] += __shfl_xor(d0[g], off);
                d1[g] += __shfl_xor(d1[g], off);
                d2[g] += __shfl_xor(d2[g], off);
            }
        }
        if (p < SEQ) {
            const float i_ = sigmoidf_(xg0[p * G4 + 0 * HID + j] + d0[0]);
            const float f_ = sigmoidf_(xg0[p * G4 + 1 * HID + j] + d0[1]);
            const float g_ = tanhf_  (xg0[p * G4 + 2 * HID + j] + d0[2]);
            const float o_ = sigmoidf_(xg0[p * G4 + 3 * HID + j] + d0[3]);
            c0 = f_ * c0 + i_ * g_;
            const float h1v = o_ * tanhf_(c0);
            if (ln == 0) h1w[j] = h1v;
        }
        if (p >= 1) {
            const float i_ = sigmoidf_(d1[0] + bias1[0] + d2[0]);
            const float f_ = sigmoidf_(d1[1] + bias1[1] + d2[1]);
            const float g_ = tanhf_  (d1[2] + bias1[2] + d2[2]);
            const float o_ = sigmoidf_(d1[3] + bias1[3] + d2[3]);
            c1 = f_ * c1 + i_ * g_;
            const float h2v = o_ * tanhf_(c1);
            if (ln == 0) {
                h2w[j] = h2v;
                out[HID + (p - 1) * HID + j] = h2v;
                if (p == SEQ) out[j] = h2v;
            }
        }
        __threadfence();
        grid.sync();
    }
}

// ---------------------------------------------------------------------------
// FALLBACK path (proven in R1): generic xg gemm + per-step kernel.
// ---------------------------------------------------------------------------
__global__ void xg_gemm(const float* __restrict__ x, const float* __restrict__ w,
                        const float* __restrict__ b_ih, const float* __restrict__ b_hh,
                        float* __restrict__ xg, int K) {
    const int g = blockIdx.x, tid = threadIdx.x, wave = tid >> 6, lane = tid & 63;
    float acc[SEQ];
#pragma unroll
    for (int t = 0; t < SEQ; ++t) acc[t] = 0.f;
    const float* wrow = w + (size_t)g * K;
    const int per = K >> 8;
    for (int e = 0; e < per; ++e) {
        const int d = tid + (e << 8);
        const float wv = wrow[d];
#pragma unroll
        for (int t = 0; t < SEQ; ++t) acc[t] += wv * x[t * K + d];
    }
    __shared__ float red[4][SEQ];
#pragma unroll
    for (int t = 0; t < SEQ; ++t) {
        float v = acc[t];
        for (int off = 32; off; off >>= 1) v += __shfl_down(v, off);
        if (lane == 0) red[wave][t] = v;
    }
    __syncthreads();
    if (tid < SEQ) {
        const int t = tid;
        xg[t * G4 + g] = red[0][t] + red[1][t] + red[2][t] + red[3][t] + b_ih[g] + b_hh[g];
    }
}

__global__ void lstm_step(const float* __restrict__ w_hh, const float* __restrict__ xg_t,
                          const float* __restrict__ h_prev, const float* __restrict__ c_prev,
                          float* __restrict__ c_out, float* __restrict__ h_out,
                          float* __restrict__ h_out2) {
    const int j = blockIdx.x, tid = threadIdx.x, wave = tid >> 6, lane = tid & 63;
    __shared__ float hs[HID];
    __shared__ float gate_s[4];
    float gacc = 0.f;
    if (h_prev != nullptr) {
        for (int i = tid; i < HID; i += 256) hs[i] = h_prev[i];
        __syncthreads();
        const float4* w4 = (const float4*)(w_hh + (size_t)(wave * HID + j) * HID);
        const float4* h4 = (const float4*)hs;
        float acc = 0.f;
#pragma unroll
        for (int e = 0; e < 4; ++e) acc += dot4(w4[lane + (e << 6)], h4[lane + (e << 6)]);
        for (int off = 32; off; off >>= 1) acc += __shfl_down(acc, off);
        gacc = acc;
    }
    if (lane == 0) gate_s[wave] = gacc;
    __syncthreads();
    if (tid == 0) {
        float i_ = sigmoidf_(xg_t[j] + gate_s[0]);
        float f_ = sigmoidf_(xg_t[j + HID] + gate_s[1]);
        float g_ = tanhf_(xg_t[j + 2 * HID] + gate_s[2]);
        float o_ = sigmoidf_(xg_t[j + 3 * HID] + gate_s[3]);
        const float cp = (c_prev != nullptr) ? c_prev[j] : 0.f;
        const float c_ = f_ * cp + i_ * g_;
        const float h_ = o_ * tanhf_(c_);
        c_out[j] = c_;
        h_out[j] = h_;
        if (h_out2 != nullptr) h_out2[j] = h_;
    }
}

extern "C" void kernel_launch(void* const* d_in, const int* in_sizes, int n_in,
                              void* d_out, int out_size, void* d_ws, size_t ws_size,
                              hipStream_t stream) {
    const float* x     = (const float*)d_in[0];
    const float* w_ih0 = (const float*)d_in[1];
    const float* w_hh0 = (const float*)d_in[2];
    const float* b_ih0 = (const float*)d_in[3];
    const float* b_hh0 = (const float*)d_in[4];
    const float* w_ih1 = (const float*)d_in[5];
    const float* w_hh1 = (const float*)d_in[6];
    const float* b_ih1 = (const float*)d_in[7];
    const float* b_hh1 = (const float*)d_in[8];

    float* xg    = (float*)d_ws;            // 65536
    float* h1a   = xg + SEQ * G4;           // 1024
    float* h1b   = h1a + HID;               // 1024
    float* h2a   = h1b + HID;               // 1024
    float* h2b   = h2a + HID;               // 1024
    float* h1seq = h2b + HID;               // 16384 (fallback)
    float* cbuf  = h1seq + SEQ * HID;       // 1024  (fallback)
    float* out   = (float*)d_out;

    xg0_gemm<<<512, 256, 0, stream>>>(x, w_ih0, b_ih0, b_hh0, xg);

    const float* a0 = w_hh0;  const float* a1 = w_ih1;  const float* a2 = w_hh1;
    const float* a3 = b_ih1;  const float* a4 = b_hh1;  const float* a5 = xg;
    float* a6 = h1a; float* a7 = h1b; float* a8 = h2a; float* a9 = h2b; float* a10 = out;
    void* args[] = { &a0, &a1, &a2, &a3, &a4, &a5, &a6, &a7, &a8, &a9, &a10 };
    hipError_t err = hipLaunchCooperativeKernel((const void*)fused_lstm, dim3(1024),
                                                dim3(64), args, 0, stream);
    if (err != hipSuccess) {
        // ---- proven fallback: per-step kernels ----
        for (int t = 0; t < SEQ; ++t) {
            const float* hp = (t == 0) ? nullptr : (h1seq + (t - 1) * HID);
            const float* cp = (t == 0) ? nullptr : cbuf;
            lstm_step<<<HID, 256, 0, stream>>>(w_hh0, xg + t * G4, hp, cp,
                                               cbuf, h1seq + t * HID, nullptr);
        }
        xg_gemm<<<G4, 256, 0, stream>>>(h1seq, w_ih1, b_ih1, b_hh1, xg, HID);
        float* h2 = out + HID;
        for (int t = 0; t < SEQ; ++t) {
            const float* hp = (t == 0) ? nullptr : (h2 + (t - 1) * HID);
            const float* cp = (t == 0) ? nullptr : cbuf;
            lstm_step<<<HID, 256, 0, stream>>>(w_hh1, xg + t * G4, hp, cp,
                                               cbuf, h2 + t * HID,
                                               (t == 15) ? out : nullptr);
        }
    }
}

// Round 4
// 921.362 us; speedup vs baseline: 2.7170x; 2.7170x over previous
//
#include <hip/hip_runtime.h>
#include <math.h>

#define SEQ 16
#define HID 1024
#define G4 4096
#define LATENT 2048
#define NBLK 1024

__device__ __forceinline__ float sigmoidf_(float x) { return 1.f / (1.f + __expf(-x)); }
__device__ __forceinline__ float tanhf_(float x) { return 1.f - 2.f / (__expf(2.f * x) + 1.f); }
__device__ __forceinline__ float dot4(float4 a, float4 b) {
    return a.x * b.x + a.y * b.y + a.z * b.z + a.w * b.w;
}

// ---------------------------------------------------------------------------
// xg0[t][g] = x[t] . w_ih0[g] + b_ih0[g] + b_hh0[g]   (K = 2048)
// ---------------------------------------------------------------------------
__global__ __launch_bounds__(256) void xg0_gemm(const float* __restrict__ x,
                                                const float* __restrict__ w,
                                                const float* __restrict__ bi,
                                                const float* __restrict__ bh,
                                                float* __restrict__ xg) {
    __shared__ float xs[SEQ][512];  // 32 KB
    const int tid = threadIdx.x, wv = tid >> 6, ln = tid & 63;
    const int g0 = blockIdx.x * 8 + wv * 2;

    float acc0[SEQ], acc1[SEQ];
#pragma unroll
    for (int t = 0; t < SEQ; ++t) { acc0[t] = 0.f; acc1[t] = 0.f; }

    for (int ch = 0; ch < 4; ++ch) {
        __syncthreads();
        const float4* xsrc = (const float4*)x;
#pragma unroll
        for (int i = 0; i < 8; ++i) {
            const int idx = tid + i * 256;
            const int t = idx >> 7;
            const int c = idx & 127;
            ((float4*)xs)[t * 128 + c] = xsrc[t * 512 + ch * 128 + c];
        }
        __syncthreads();
        const float4* w0 = (const float4*)(w + (size_t)g0 * LATENT) + ch * 128;
        const float4* w1 = (const float4*)(w + (size_t)(g0 + 1) * LATENT) + ch * 128;
        const float4 a0 = w0[ln], a1 = w0[ln + 64];
        const float4 b0 = w1[ln], b1 = w1[ln + 64];
#pragma unroll
        for (int t = 0; t < SEQ; ++t) {
            const float4 xa = ((const float4*)xs)[t * 128 + ln];
            const float4 xb = ((const float4*)xs)[t * 128 + ln + 64];
            acc0[t] += dot4(a0, xa) + dot4(a1, xb);
            acc1[t] += dot4(b0, xa) + dot4(b1, xb);
        }
    }
#pragma unroll
    for (int t = 0; t < SEQ; ++t) {
        float v0 = acc0[t], v1 = acc1[t];
#pragma unroll
        for (int off = 32; off; off >>= 1) { v0 += __shfl_xor(v0, off); v1 += __shfl_xor(v1, off); }
        acc0[t] = v0; acc1[t] = v1;
    }
    if (ln < SEQ) {
        xg[ln * G4 + g0]     = acc0[ln] + bi[g0] + bh[g0];
        xg[ln * G4 + g0 + 1] = acc1[ln] + bi[g0 + 1] + bh[g0 + 1];
    }
}

// ---------------------------------------------------------------------------
// Fused two-layer recurrence; ONE WAVE per block, weights in VGPRs.
// Hand-rolled grid barrier (generation-based, per-block arrive slots):
//   - lane0 release-stores gen to arrive[j]   (agent scope, cross-XCD)
//   - block0's 64 lanes scan 16 slots each, then publish release=gen
//   - waiters poll release with s_sleep backoff
//   - __threadfence() before/after handles L2 writeback + invalidate
// ---------------------------------------------------------------------------
__global__ __launch_bounds__(64) void fused_lstm(
    const float* __restrict__ w_hh0,
    const float* __restrict__ w_ih1,
    const float* __restrict__ w_hh1,
    const float* __restrict__ b_ih1,
    const float* __restrict__ b_hh1,
    const float* __restrict__ xg0,
    float* __restrict__ h1a, float* __restrict__ h1b,
    float* __restrict__ h2a, float* __restrict__ h2b,
    unsigned* __restrict__ arrive, unsigned* __restrict__ release_,
    float* __restrict__ out) {
    const int j = blockIdx.x;
    const int ln = threadIdx.x;

    // ---- weights into registers: 48 float4 = 192 VGPRs ----
    float4 wa[4][4], wb[4][4], wc[4][4];
#pragma unroll
    for (int g = 0; g < 4; ++g) {
        const float4* p0 = (const float4*)w_hh0 + (size_t)(g * HID + j) * 256;
        const float4* p1 = (const float4*)w_ih1 + (size_t)(g * HID + j) * 256;
        const float4* p2 = (const float4*)w_hh1 + (size_t)(g * HID + j) * 256;
#pragma unroll
        for (int c = 0; c < 4; ++c) {
            wa[g][c] = p0[ln + 64 * c];
            wb[g][c] = p1[ln + 64 * c];
            wc[g][c] = p2[ln + 64 * c];
        }
    }
    float bias1[4];
#pragma unroll
    for (int g = 0; g < 4; ++g) bias1[g] = b_ih1[g * HID + j] + b_hh1[g * HID + j];

    float c0 = 0.f, c1 = 0.f;

    for (int p = 0; p <= SEQ; ++p) {
        const float4* h1r = (const float4*)((p & 1) ? h1a : h1b);
        const float4* h2r = (const float4*)((p & 1) ? h2a : h2b);
        float* h1w = (p & 1) ? h1b : h1a;
        float* h2w = (p & 1) ? h2b : h2a;

        float d0[4] = {0.f, 0.f, 0.f, 0.f};
        float d1[4] = {0.f, 0.f, 0.f, 0.f};
        float d2[4] = {0.f, 0.f, 0.f, 0.f};
        if (p >= 1) {
#pragma unroll
            for (int c = 0; c < 4; ++c) {
                const float4 h = h1r[ln + 64 * c];
#pragma unroll
                for (int g = 0; g < 4; ++g) {
                    d0[g] += dot4(wa[g][c], h);
                    d1[g] += dot4(wb[g][c], h);
                }
            }
        }
        if (p >= 2) {
#pragma unroll
            for (int c = 0; c < 4; ++c) {
                const float4 h = h2r[ln + 64 * c];
#pragma unroll
                for (int g = 0; g < 4; ++g) d2[g] += dot4(wc[g][c], h);
            }
        }
#pragma unroll
        for (int off = 32; off; off >>= 1) {
#pragma unroll
            for (int g = 0; g < 4; ++g) {
                d0[g] += __shfl_xor(d0[g], off);
                d1[g] += __shfl_xor(d1[g], off);
                d2[g] += __shfl_xor(d2[g], off);
            }
        }
        if (p < SEQ) {
            const float i_ = sigmoidf_(xg0[p * G4 + 0 * HID + j] + d0[0]);
            const float f_ = sigmoidf_(xg0[p * G4 + 1 * HID + j] + d0[1]);
            const float g_ = tanhf_  (xg0[p * G4 + 2 * HID + j] + d0[2]);
            const float o_ = sigmoidf_(xg0[p * G4 + 3 * HID + j] + d0[3]);
            c0 = f_ * c0 + i_ * g_;
            const float h1v = o_ * tanhf_(c0);
            if (ln == 0) h1w[j] = h1v;
        }
        if (p >= 1) {
            const float i_ = sigmoidf_(d1[0] + bias1[0] + d2[0]);
            const float f_ = sigmoidf_(d1[1] + bias1[1] + d2[1]);
            const float g_ = tanhf_  (d1[2] + bias1[2] + d2[2]);
            const float o_ = sigmoidf_(d1[3] + bias1[3] + d2[3]);
            c1 = f_ * c1 + i_ * g_;
            const float h2v = o_ * tanhf_(c1);
            if (ln == 0) {
                h2w[j] = h2v;
                out[HID + (p - 1) * HID + j] = h2v;
                if (p == SEQ) out[j] = h2v;
            }
        }

        // ---- grid barrier (skip after last phase) ----
        if (p < SEQ) {
            const unsigned gen = (unsigned)(p + 1);
            __threadfence();  // make h/out writes device-visible (L2 wb)
            if (ln == 0)
                __hip_atomic_store(&arrive[j], gen, __ATOMIC_RELEASE,
                                   __HIP_MEMORY_SCOPE_AGENT);
            if (j == 0) {
                for (int s = ln; s < NBLK; s += 64) {
                    while (__hip_atomic_load(&arrive[s], __ATOMIC_RELAXED,
                                             __HIP_MEMORY_SCOPE_AGENT) != gen)
                        __builtin_amdgcn_s_sleep(1);
                }
                __threadfence();  // order scan loads before release store
                if (ln == 0)
                    __hip_atomic_store(release_, gen, __ATOMIC_RELEASE,
                                       __HIP_MEMORY_SCOPE_AGENT);
            } else {
                if (ln == 0) {
                    while (__hip_atomic_load(release_, __ATOMIC_RELAXED,
                                             __HIP_MEMORY_SCOPE_AGENT) != gen)
                        __builtin_amdgcn_s_sleep(1);
                }
            }
            __threadfence();  // acquire: invalidate L1/L2 so h reads are fresh
        }
    }
}

// ---------------------------------------------------------------------------
// FALLBACK path (proven in R1): generic xg gemm + per-step kernel.
// ---------------------------------------------------------------------------
__global__ void xg_gemm(const float* __restrict__ x, const float* __restrict__ w,
                        const float* __restrict__ b_ih, const float* __restrict__ b_hh,
                        float* __restrict__ xg, int K) {
    const int g = blockIdx.x, tid = threadIdx.x, wave = tid >> 6, lane = tid & 63;
    float acc[SEQ];
#pragma unroll
    for (int t = 0; t < SEQ; ++t) acc[t] = 0.f;
    const float* wrow = w + (size_t)g * K;
    const int per = K >> 8;
    for (int e = 0; e < per; ++e) {
        const int d = tid + (e << 8);
        const float wv = wrow[d];
#pragma unroll
        for (int t = 0; t < SEQ; ++t) acc[t] += wv * x[t * K + d];
    }
    __shared__ float red[4][SEQ];
#pragma unroll
    for (int t = 0; t < SEQ; ++t) {
        float v = acc[t];
        for (int off = 32; off; off >>= 1) v += __shfl_down(v, off);
        if (lane == 0) red[wave][t] = v;
    }
    __syncthreads();
    if (tid < SEQ) {
        const int t = tid;
        xg[t * G4 + g] = red[0][t] + red[1][t] + red[2][t] + red[3][t] + b_ih[g] + b_hh[g];
    }
}

__global__ void lstm_step(const float* __restrict__ w_hh, const float* __restrict__ xg_t,
                          const float* __restrict__ h_prev, const float* __restrict__ c_prev,
                          float* __restrict__ c_out, float* __restrict__ h_out,
                          float* __restrict__ h_out2) {
    const int j = blockIdx.x, tid = threadIdx.x, wave = tid >> 6, lane = tid & 63;
    __shared__ float hs[HID];
    __shared__ float gate_s[4];
    float gacc = 0.f;
    if (h_prev != nullptr) {
        for (int i = tid; i < HID; i += 256) hs[i] = h_prev[i];
        __syncthreads();
        const float4* w4 = (const float4*)(w_hh + (size_t)(wave * HID + j) * HID);
        const float4* h4 = (const float4*)hs;
        float acc = 0.f;
#pragma unroll
        for (int e = 0; e < 4; ++e) acc += dot4(w4[lane + (e << 6)], h4[lane + (e << 6)]);
        for (int off = 32; off; off >>= 1) acc += __shfl_down(acc, off);
        gacc = acc;
    }
    if (lane == 0) gate_s[wave] = gacc;
    __syncthreads();
    if (tid == 0) {
        float i_ = sigmoidf_(xg_t[j] + gate_s[0]);
        float f_ = sigmoidf_(xg_t[j + HID] + gate_s[1]);
        float g_ = tanhf_(xg_t[j + 2 * HID] + gate_s[2]);
        float o_ = sigmoidf_(xg_t[j + 3 * HID] + gate_s[3]);
        const float cp = (c_prev != nullptr) ? c_prev[j] : 0.f;
        const float c_ = f_ * cp + i_ * g_;
        const float h_ = o_ * tanhf_(c_);
        c_out[j] = c_;
        h_out[j] = h_;
        if (h_out2 != nullptr) h_out2[j] = h_;
    }
}

extern "C" void kernel_launch(void* const* d_in, const int* in_sizes, int n_in,
                              void* d_out, int out_size, void* d_ws, size_t ws_size,
                              hipStream_t stream) {
    const float* x     = (const float*)d_in[0];
    const float* w_ih0 = (const float*)d_in[1];
    const float* w_hh0 = (const float*)d_in[2];
    const float* b_ih0 = (const float*)d_in[3];
    const float* b_hh0 = (const float*)d_in[4];
    const float* w_ih1 = (const float*)d_in[5];
    const float* w_hh1 = (const float*)d_in[6];
    const float* b_ih1 = (const float*)d_in[7];
    const float* b_hh1 = (const float*)d_in[8];

    float* xg    = (float*)d_ws;            // 65536
    float* h1a   = xg + SEQ * G4;           // 1024
    float* h1b   = h1a + HID;               // 1024
    float* h2a   = h1b + HID;               // 1024
    float* h2b   = h2a + HID;               // 1024
    float* h1seq = h2b + HID;               // 16384 (fallback)
    float* cbuf  = h1seq + SEQ * HID;       // 1024  (fallback)
    unsigned* arrive   = (unsigned*)(cbuf + HID);   // 1024 uints
    unsigned* release_ = arrive + NBLK;             // 1 uint (+pad)
    float* out   = (float*)d_out;

    xg0_gemm<<<512, 256, 0, stream>>>(x, w_ih0, b_ih0, b_hh0, xg);

    const float* a0 = w_hh0;  const float* a1 = w_ih1;  const float* a2 = w_hh1;
    const float* a3 = b_ih1;  const float* a4 = b_hh1;  const float* a5 = xg;
    float* a6 = h1a; float* a7 = h1b; float* a8 = h2a; float* a9 = h2b;
    unsigned* a10 = arrive; unsigned* a11 = release_;
    float* a12 = out;
    void* args[] = { &a0, &a1, &a2, &a3, &a4, &a5, &a6, &a7, &a8, &a9,
                     &a10, &a11, &a12 };
    hipError_t err = hipLaunchCooperativeKernel((const void*)fused_lstm, dim3(NBLK),
                                                dim3(64), args, 0, stream);
    if (err != hipSuccess) {
        // ---- proven fallback: per-step kernels ----
        for (int t = 0; t < SEQ; ++t) {
            const float* hp = (t == 0) ? nullptr : (h1seq + (t - 1) * HID);
            const float* cp = (t == 0) ? nullptr : cbuf;
            lstm_step<<<HID, 256, 0, stream>>>(w_hh0, xg + t * G4, hp, cp,
                                               cbuf, h1seq + t * HID, nullptr);
        }
        xg_gemm<<<G4, 256, 0, stream>>>(h1seq, w_ih1, b_ih1, b_hh1, xg, HID);
        float* h2 = out + HID;
        for (int t = 0; t < SEQ; ++t) {
            const float* hp = (t == 0) ? nullptr : (h2 + (t - 1) * HID);
            const float* cp = (t == 0) ? nullptr : cbuf;
            lstm_step<<<HID, 256, 0, stream>>>(w_hh1, xg + t * G4, hp, cp,
                                               cbuf, h2 + t * HID,
                                               (t == 15) ? out : nullptr);
        }
    }
}